// Round 1
// baseline (1268.501 us; speedup 1.0000x reference)
//
#include <hip/hip_runtime.h>
#include <hip/hip_bf16.h>

#define NNUE_INPUTS 41024
#define NNUE_L1 128
#define NNUE_L2 32
#define NNUE_L3 32
#define MAX_ACT 1024   // per-perspective active-feature list capacity (expect ~30, Poisson tail << 1024)

__device__ __forceinline__ float clip01(float x) {
    return fminf(fmaxf(x, 0.0f), 1.0f);
}

__global__ __launch_bounds__(256, 2) void nnue_fused_kernel(
    const float* __restrict__ us, const float* __restrict__ them,
    const float* __restrict__ w_in, const float* __restrict__ b_in,
    const float* __restrict__ W_ft, const float* __restrict__ b_ft,
    const float* __restrict__ W1, const float* __restrict__ b1,
    const float* __restrict__ W2, const float* __restrict__ b2,
    const float* __restrict__ Wo, const float* __restrict__ bo,
    float* __restrict__ out)
{
    __shared__ int   s_idx_w[MAX_ACT];
    __shared__ int   s_idx_b[MAX_ACT];
    __shared__ int   s_cnt[2];
    __shared__ float s_w[NNUE_L1];
    __shared__ float s_b[NNUE_L1];
    __shared__ float s_l0[2 * NNUE_L1];
    __shared__ float s_l1[NNUE_L2];
    __shared__ float s_l2[NNUE_L3];

    const int row = blockIdx.x;
    const int tid = threadIdx.x;

    if (tid < 2) s_cnt[tid] = 0;
    __syncthreads();

    // ---- Phase 1: scan both sparse mask rows (float4 = 16B/lane), collect nonzero indices ----
    const float4* wrow = (const float4*)(w_in + (size_t)row * NNUE_INPUTS);
    const float4* brow = (const float4*)(b_in + (size_t)row * NNUE_INPUTS);
    const int nvec = NNUE_INPUTS / 4;  // 10256

    for (int v = tid; v < nvec; v += 256) {
        float4 a = wrow[v];
        float4 c = brow[v];
        int base = v * 4;
        if (a.x != 0.0f) { int p = atomicAdd(&s_cnt[0], 1); if (p < MAX_ACT) s_idx_w[p] = base;     }
        if (a.y != 0.0f) { int p = atomicAdd(&s_cnt[0], 1); if (p < MAX_ACT) s_idx_w[p] = base + 1; }
        if (a.z != 0.0f) { int p = atomicAdd(&s_cnt[0], 1); if (p < MAX_ACT) s_idx_w[p] = base + 2; }
        if (a.w != 0.0f) { int p = atomicAdd(&s_cnt[0], 1); if (p < MAX_ACT) s_idx_w[p] = base + 3; }
        if (c.x != 0.0f) { int p = atomicAdd(&s_cnt[1], 1); if (p < MAX_ACT) s_idx_b[p] = base;     }
        if (c.y != 0.0f) { int p = atomicAdd(&s_cnt[1], 1); if (p < MAX_ACT) s_idx_b[p] = base + 1; }
        if (c.z != 0.0f) { int p = atomicAdd(&s_cnt[1], 1); if (p < MAX_ACT) s_idx_b[p] = base + 2; }
        if (c.w != 0.0f) { int p = atomicAdd(&s_cnt[1], 1); if (p < MAX_ACT) s_idx_b[p] = base + 3; }
    }
    __syncthreads();

    const int kw = min(s_cnt[0], MAX_ACT);
    const int kb = min(s_cnt[1], MAX_ACT);

    // ---- Phase 2: accumulate W_ft rows for active features ----
    // threads [0,128): w-perspective channel c=tid; threads [128,256): b-perspective channel c=tid-128
    {
        const int  c    = tid & (NNUE_L1 - 1);
        const bool is_b = tid >= NNUE_L1;
        const int* lst  = is_b ? s_idx_b : s_idx_w;
        const int  K    = is_b ? kb : kw;
        float acc = b_ft[c];
        for (int k = 0; k < K; ++k) {
            acc += W_ft[(size_t)lst[k] * NNUE_L1 + c];   // 512B coalesced per group
        }
        if (is_b) s_b[c] = acc; else s_w[c] = acc;
    }
    __syncthreads();

    // ---- Phase 3: perspective mix + clip -> l0 [256] ----
    const float u = us[row];
    const float t = them[row];
    if (tid < NNUE_L1) {
        float wv = s_w[tid], bv = s_b[tid];
        s_l0[tid]            = clip01(u * wv + t * bv);
        s_l0[NNUE_L1 + tid]  = clip01(u * bv + t * wv);
    }
    __syncthreads();

    // ---- l1 = clip(l0 @ W1 + b1)  [256 x 32] ----
    if (tid < NNUE_L2) {
        float a = b1[tid];
        #pragma unroll 8
        for (int k = 0; k < 2 * NNUE_L1; ++k) {
            a += s_l0[k] * W1[k * NNUE_L2 + tid];
        }
        s_l1[tid] = clip01(a);
    }
    __syncthreads();

    // ---- l2 = clip(l1 @ W2 + b2)  [32 x 32] ----
    if (tid < NNUE_L3) {
        float a = b2[tid];
        #pragma unroll
        for (int k = 0; k < NNUE_L2; ++k) {
            a += s_l1[k] * W2[k * NNUE_L3 + tid];
        }
        s_l2[tid] = clip01(a);
    }
    __syncthreads();

    // ---- out = l2 @ Wo + bo ----
    if (tid == 0) {
        float a = bo[0];
        #pragma unroll
        for (int k = 0; k < NNUE_L3; ++k) {
            a += s_l2[k] * Wo[k];
        }
        out[row] = a;
    }
}

extern "C" void kernel_launch(void* const* d_in, const int* in_sizes, int n_in,
                              void* d_out, int out_size, void* d_ws, size_t ws_size,
                              hipStream_t stream) {
    const float* us   = (const float*)d_in[0];
    const float* them = (const float*)d_in[1];
    const float* w_in = (const float*)d_in[2];
    const float* b_in = (const float*)d_in[3];
    const float* W_ft = (const float*)d_in[4];
    const float* b_ft = (const float*)d_in[5];
    const float* W1   = (const float*)d_in[6];
    const float* b1   = (const float*)d_in[7];
    const float* W2   = (const float*)d_in[8];
    const float* b2   = (const float*)d_in[9];
    const float* Wo   = (const float*)d_in[10];
    const float* bo   = (const float*)d_in[11];
    float* out = (float*)d_out;

    const int B = in_sizes[0];  // 4096 rows (us is [B,1])
    nnue_fused_kernel<<<dim3(B), dim3(256), 0, stream>>>(
        us, them, w_in, b_in, W_ft, b_ft, W1, b1, W2, b2, Wo, bo, out);
}

// Round 2
// 1233.769 us; speedup vs baseline: 1.0282x; 1.0282x over previous
//
#include <hip/hip_runtime.h>
#include <hip/hip_bf16.h>

#define NNUE_INPUTS 41024
#define L1N 128
#define L2N 32
#define L3N 32
#define MAX_ACT 512   // per-perspective capacity; mean ~30 actives, P(>512) ~ 0

__device__ __forceinline__ float clip01(float x) {
    return fminf(fmaxf(x, 0.0f), 1.0f);
}

__global__ __launch_bounds__(256, 4) void nnue_fused_kernel(
    const float* __restrict__ us, const float* __restrict__ them,
    const float* __restrict__ w_in, const float* __restrict__ b_in,
    const float* __restrict__ W_ft, const float* __restrict__ b_ft,
    const float* __restrict__ W1, const float* __restrict__ b1,
    const float* __restrict__ W2, const float* __restrict__ b2,
    const float* __restrict__ Wo, const float* __restrict__ bo,
    float* __restrict__ out)
{
    __shared__ int   s_idx_w[MAX_ACT];
    __shared__ int   s_idx_b[MAX_ACT];
    __shared__ int   s_cnt[2];
    __shared__ float s_w[L1N];
    __shared__ float s_b[L1N];
    __shared__ float s_l0[2 * L1N];
    __shared__ float s_part[8][L2N];
    __shared__ float s_l1[L2N];
    __shared__ float s_l2[L3N];

    const int row = blockIdx.x;
    const int tid = threadIdx.x;

    if (tid < 2) s_cnt[tid] = 0;
    // issue these scalar-ish loads early; used long after
    const float u = us[row];
    const float t = them[row];
    __syncthreads();

    // ---- Phase 1: scan both mask rows, 64 B/thread/iter (4x float4 in flight) ----
    const float4* wr = (const float4*)(w_in + (size_t)row * NNUE_INPUTS);
    const float4* br = (const float4*)(b_in + (size_t)row * NNUE_INPUTS);
    const int nv8 = NNUE_INPUTS / 8;   // 5128, exact

    for (int v = tid; v < nv8; v += 256) {
        const float4 a0 = wr[2 * v];
        const float4 a1 = wr[2 * v + 1];
        const float4 c0 = br[2 * v];
        const float4 c1 = br[2 * v + 1];
        // mask values are exactly 0.0/1.0 -> sums are exact; nonzero sum == any active
        const float sw = ((a0.x + a0.y) + (a0.z + a0.w)) + ((a1.x + a1.y) + (a1.z + a1.w));
        const float sb = ((c0.x + c0.y) + (c0.z + c0.w)) + ((c1.x + c1.y) + (c1.z + c1.w));
        if (__any((sw != 0.0f) || (sb != 0.0f))) {       // one branch per wave-iter
            const int base = v * 8;
            if (sw != 0.0f) {
                unsigned m = (a0.x != 0.0f ?   1u : 0u) | (a0.y != 0.0f ?   2u : 0u)
                           | (a0.z != 0.0f ?   4u : 0u) | (a0.w != 0.0f ?   8u : 0u)
                           | (a1.x != 0.0f ?  16u : 0u) | (a1.y != 0.0f ?  32u : 0u)
                           | (a1.z != 0.0f ?  64u : 0u) | (a1.w != 0.0f ? 128u : 0u);
                while (m) {
                    const int b = __ffs(m) - 1; m &= m - 1;
                    const int p = atomicAdd(&s_cnt[0], 1);
                    s_idx_w[p & (MAX_ACT - 1)] = base + b;
                }
            }
            if (sb != 0.0f) {
                unsigned m = (c0.x != 0.0f ?   1u : 0u) | (c0.y != 0.0f ?   2u : 0u)
                           | (c0.z != 0.0f ?   4u : 0u) | (c0.w != 0.0f ?   8u : 0u)
                           | (c1.x != 0.0f ?  16u : 0u) | (c1.y != 0.0f ?  32u : 0u)
                           | (c1.z != 0.0f ?  64u : 0u) | (c1.w != 0.0f ? 128u : 0u);
                while (m) {
                    const int b = __ffs(m) - 1; m &= m - 1;
                    const int p = atomicAdd(&s_cnt[1], 1);
                    s_idx_b[p & (MAX_ACT - 1)] = base + b;
                }
            }
        }
    }
    __syncthreads();

    const int kw = min(s_cnt[0], MAX_ACT);
    const int kb = min(s_cnt[1], MAX_ACT);

    // ---- Phase 2: gather W_ft rows; unroll-4 independent loads ----
    {
        const int  c    = tid & (L1N - 1);
        const bool is_b = tid >= L1N;
        const int* lst  = is_b ? s_idx_b : s_idx_w;
        const int  K    = is_b ? kb : kw;
        const float* Wc = W_ft + c;
        float acc = b_ft[c];
        int k = 0;
        for (; k + 4 <= K; k += 4) {
            const int i0 = lst[k], i1 = lst[k + 1], i2 = lst[k + 2], i3 = lst[k + 3];
            const float f0 = Wc[(size_t)i0 * L1N];
            const float f1 = Wc[(size_t)i1 * L1N];
            const float f2 = Wc[(size_t)i2 * L1N];
            const float f3 = Wc[(size_t)i3 * L1N];
            acc += f0; acc += f1; acc += f2; acc += f3;
        }
        for (; k < K; ++k) acc += Wc[(size_t)lst[k] * L1N];
        if (is_b) s_b[c] = acc; else s_w[c] = acc;
    }
    __syncthreads();

    // ---- Phase 3: perspective mix + clip -> l0 [256] ----
    if (tid < L1N) {
        const float wv = s_w[tid], bv = s_b[tid];
        s_l0[tid]       = clip01(u * wv + t * bv);
        s_l0[L1N + tid] = clip01(u * bv + t * wv);
    }
    __syncthreads();

    // ---- l1 = clip(l0 @ W1 + b1): 256 threads = 8 chunks x 32 outputs ----
    {
        const int o  = tid & 31;
        const int ch = tid >> 5;
        float a = 0.0f;
        const int k0 = ch * 32;
        #pragma unroll
        for (int k = 0; k < 32; ++k) {
            a += s_l0[k0 + k] * W1[(k0 + k) * L2N + o];
        }
        s_part[ch][o] = a;
    }
    __syncthreads();
    if (tid < L2N) {
        float a = b1[tid];
        #pragma unroll
        for (int j = 0; j < 8; ++j) a += s_part[j][tid];
        s_l1[tid] = clip01(a);
    }
    __syncthreads();

    // ---- l2 = clip(l1 @ W2 + b2) ----
    if (tid < L3N) {
        float a = b2[tid];
        #pragma unroll
        for (int k = 0; k < L2N; ++k) a += s_l1[k] * W2[k * L3N + tid];
        s_l2[tid] = clip01(a);
    }
    __syncthreads();

    // ---- out = l2 @ Wo + bo ----
    if (tid == 0) {
        float a = bo[0];
        #pragma unroll
        for (int k = 0; k < L3N; ++k) a += s_l2[k] * Wo[k];
        out[row] = a;
    }
}

extern "C" void kernel_launch(void* const* d_in, const int* in_sizes, int n_in,
                              void* d_out, int out_size, void* d_ws, size_t ws_size,
                              hipStream_t stream) {
    const float* us   = (const float*)d_in[0];
    const float* them = (const float*)d_in[1];
    const float* w_in = (const float*)d_in[2];
    const float* b_in = (const float*)d_in[3];
    const float* W_ft = (const float*)d_in[4];
    const float* b_ft = (const float*)d_in[5];
    const float* W1   = (const float*)d_in[6];
    const float* b1   = (const float*)d_in[7];
    const float* W2   = (const float*)d_in[8];
    const float* b2   = (const float*)d_in[9];
    const float* Wo   = (const float*)d_in[10];
    const float* bo   = (const float*)d_in[11];
    float* out = (float*)d_out;

    const int B = in_sizes[0];  // 4096
    nnue_fused_kernel<<<dim3(B), dim3(256), 0, stream>>>(
        us, them, w_in, b_in, W_ft, b_ft, W1, b1, W2, b2, Wo, bo, out);
}

// Round 3
// 1233.183 us; speedup vs baseline: 1.0286x; 1.0005x over previous
//
#include <hip/hip_runtime.h>
#include <hip/hip_bf16.h>

#define NNUE_INPUTS 41024
#define L1N 128
#define L2N 32
#define L3N 32
#define MAX_ACT 512     // per-perspective capacity; mean ~30 actives
#define NV8 (NNUE_INPUTS / 8)      // 5128 chunks of 8 floats (32B)
#define BULK 20                    // 20*256 = 5120 uniform chunks; tail = 8

__device__ __forceinline__ float clip01(float x) {
    return fminf(fmaxf(x, 0.0f), 1.0f);
}

__global__ __launch_bounds__(256, 4) void nnue_fused_kernel(
    const float* __restrict__ us, const float* __restrict__ them,
    const float* __restrict__ w_in, const float* __restrict__ b_in,
    const float* __restrict__ W_ft, const float* __restrict__ b_ft,
    const float* __restrict__ W1, const float* __restrict__ b1,
    const float* __restrict__ W2, const float* __restrict__ b2,
    const float* __restrict__ Wo, const float* __restrict__ bo,
    float* __restrict__ out)
{
    __shared__ int   s_idx_w[MAX_ACT];
    __shared__ int   s_idx_b[MAX_ACT];
    __shared__ int   s_cnt[2];
    __shared__ float s_w[L1N];
    __shared__ float s_b[L1N];
    __shared__ float s_l0[2 * L1N];
    __shared__ float s_part[8][L2N];
    __shared__ float s_l1[L2N];
    __shared__ float s_l2[L3N];

    const int row = blockIdx.x;
    const int tid = threadIdx.x;

    if (tid < 2) s_cnt[tid] = 0;
    const float u = us[row];
    const float t = them[row];
    __syncthreads();

    const float4* wr = (const float4*)(w_in + (size_t)row * NNUE_INPUTS);
    const float4* br = (const float4*)(b_in + (size_t)row * NNUE_INPUTS);

    // ---- Phase 1: software-pipelined scan.
    // Chunk v covers floats [8v, 8v+8). Bulk: v = tid + i*256, i in [0,20) -> v < 5120 uniformly.
    // Prefetch chunk i+1 BEFORE consuming chunk i, so 4 loads stay in flight across each wait.
    auto process = [&](int v, float4 a0, float4 a1, float4 c0, float4 c1) {
        const float sw = ((a0.x + a0.y) + (a0.z + a0.w)) + ((a1.x + a1.y) + (a1.z + a1.w));
        const float sb = ((c0.x + c0.y) + (c0.z + c0.w)) + ((c1.x + c1.y) + (c1.z + c1.w));
        if (__any((sw != 0.0f) || (sb != 0.0f))) {
            const int base = v * 8;
            if (sw != 0.0f) {
                unsigned m = (a0.x != 0.0f ?   1u : 0u) | (a0.y != 0.0f ?   2u : 0u)
                           | (a0.z != 0.0f ?   4u : 0u) | (a0.w != 0.0f ?   8u : 0u)
                           | (a1.x != 0.0f ?  16u : 0u) | (a1.y != 0.0f ?  32u : 0u)
                           | (a1.z != 0.0f ?  64u : 0u) | (a1.w != 0.0f ? 128u : 0u);
                while (m) {
                    const int b = __ffs(m) - 1; m &= m - 1;
                    const int p = atomicAdd(&s_cnt[0], 1);
                    s_idx_w[p & (MAX_ACT - 1)] = base + b;
                }
            }
            if (sb != 0.0f) {
                unsigned m = (c0.x != 0.0f ?   1u : 0u) | (c0.y != 0.0f ?   2u : 0u)
                           | (c0.z != 0.0f ?   4u : 0u) | (c0.w != 0.0f ?   8u : 0u)
                           | (c1.x != 0.0f ?  16u : 0u) | (c1.y != 0.0f ?  32u : 0u)
                           | (c1.z != 0.0f ?  64u : 0u) | (c1.w != 0.0f ? 128u : 0u);
                while (m) {
                    const int b = __ffs(m) - 1; m &= m - 1;
                    const int p = atomicAdd(&s_cnt[1], 1);
                    s_idx_b[p & (MAX_ACT - 1)] = base + b;
                }
            }
        }
    };

    {
        int v = tid;
        float4 a0 = wr[2 * v], a1 = wr[2 * v + 1];
        float4 c0 = br[2 * v], c1 = br[2 * v + 1];
        #pragma unroll 1
        for (int i = 0; i < BULK - 1; ++i) {
            const int vn = v + 256;
            const float4 na0 = wr[2 * vn], na1 = wr[2 * vn + 1];
            const float4 nc0 = br[2 * vn], nc1 = br[2 * vn + 1];
            process(v, a0, a1, c0, c1);
            a0 = na0; a1 = na1; c0 = nc0; c1 = nc1;
            v = vn;
        }
        process(v, a0, a1, c0, c1);
        // tail: chunks [5120, 5128) handled by threads 0..7
        const int vt = BULK * 256 + tid;
        if (vt < NV8) {
            process(vt, wr[2 * vt], wr[2 * vt + 1], br[2 * vt], br[2 * vt + 1]);
        }
    }
    __syncthreads();

    const int kw = min(s_cnt[0], MAX_ACT);
    const int kb = min(s_cnt[1], MAX_ACT);

    // ---- Phase 2: gather W_ft rows; unroll-4 independent loads ----
    {
        const int  c    = tid & (L1N - 1);
        const bool is_b = tid >= L1N;
        const int* lst  = is_b ? s_idx_b : s_idx_w;
        const int  K    = is_b ? kb : kw;
        const float* Wc = W_ft + c;
        float acc = b_ft[c];
        int k = 0;
        for (; k + 4 <= K; k += 4) {
            const int i0 = lst[k], i1 = lst[k + 1], i2 = lst[k + 2], i3 = lst[k + 3];
            const float f0 = Wc[(size_t)i0 * L1N];
            const float f1 = Wc[(size_t)i1 * L1N];
            const float f2 = Wc[(size_t)i2 * L1N];
            const float f3 = Wc[(size_t)i3 * L1N];
            acc += f0; acc += f1; acc += f2; acc += f3;
        }
        for (; k < K; ++k) acc += Wc[(size_t)lst[k] * L1N];
        if (is_b) s_b[c] = acc; else s_w[c] = acc;
    }
    __syncthreads();

    // ---- Phase 3: perspective mix + clip -> l0 [256] ----
    if (tid < L1N) {
        const float wv = s_w[tid], bv = s_b[tid];
        s_l0[tid]       = clip01(u * wv + t * bv);
        s_l0[L1N + tid] = clip01(u * bv + t * wv);
    }
    __syncthreads();

    // ---- l1 = clip(l0 @ W1 + b1): 256 threads = 8 chunks x 32 outputs ----
    {
        const int o  = tid & 31;
        const int ch = tid >> 5;
        float a = 0.0f;
        const int k0 = ch * 32;
        #pragma unroll
        for (int k = 0; k < 32; ++k) {
            a += s_l0[k0 + k] * W1[(k0 + k) * L2N + o];
        }
        s_part[ch][o] = a;
    }
    __syncthreads();
    if (tid < L2N) {
        float a = b1[tid];
        #pragma unroll
        for (int j = 0; j < 8; ++j) a += s_part[j][tid];
        s_l1[tid] = clip01(a);
    }
    __syncthreads();

    // ---- l2 = clip(l1 @ W2 + b2) ----
    if (tid < L3N) {
        float a = b2[tid];
        #pragma unroll
        for (int k = 0; k < L2N; ++k) a += s_l1[k] * W2[k * L3N + tid];
        s_l2[tid] = clip01(a);
    }
    __syncthreads();

    // ---- out = l2 @ Wo + bo ----
    if (tid == 0) {
        float a = bo[0];
        #pragma unroll
        for (int k = 0; k < L3N; ++k) a += s_l2[k] * Wo[k];
        out[row] = a;
    }
}

extern "C" void kernel_launch(void* const* d_in, const int* in_sizes, int n_in,
                              void* d_out, int out_size, void* d_ws, size_t ws_size,
                              hipStream_t stream) {
    const float* us   = (const float*)d_in[0];
    const float* them = (const float*)d_in[1];
    const float* w_in = (const float*)d_in[2];
    const float* b_in = (const float*)d_in[3];
    const float* W_ft = (const float*)d_in[4];
    const float* b_ft = (const float*)d_in[5];
    const float* W1   = (const float*)d_in[6];
    const float* b1   = (const float*)d_in[7];
    const float* W2   = (const float*)d_in[8];
    const float* b2   = (const float*)d_in[9];
    const float* Wo   = (const float*)d_in[10];
    const float* bo   = (const float*)d_in[11];
    float* out = (float*)d_out;

    const int B = in_sizes[0];  // 4096
    nnue_fused_kernel<<<dim3(B), dim3(256), 0, stream>>>(
        us, them, w_in, b_in, W_ft, b_ft, W1, b1, W2, b2, Wo, bo, out);
}